// Round 9
// baseline (89.005 us; speedup 1.0000x reference)
//
#include <hip/hip_runtime.h>

// Chamfer distance, B=16, N=M=4096, 2-D fp32 points, prefix-length masks.
// d_out: [fwd 16*4096][bwd 16*4096] fp32.
//
// R15: ONE dispatch, single-writer blocks, zero atomics, zero ws, no init.
//  - Gap model (R11 A/B: +19.7us per extra dispatch; R14: swapping
//    reduce->memset saved only 3.6): dur ~= fill(40) + ~8-10us PER DISPATCH
//    + kernel time. R14 still paid memset dispatch + ~1M atomic drain.
//  - Single-writer: block = (row, 128-query slice); scans the whole valid
//    search prefix via LDS chunks; plain coalesced stores. Every output
//    element has exactly one writer -> no init needed, no coherence issues.
//  - R7's failure (NQ=1, LDS latency exposed) fixed with NQ=8: 24 VALU per
//    2 broadcast LDS reads. R8's failure (thin blocks, imbalance) fixed:
//    1024 blocks x 256 thr (4 waves), ~540 active -> ~2 blocks/CU; search
//    split 16-way inside the block (worst-row serial span 2048/16*48cy =
//    6.1Kcy ~= 2.6us), LDS 16-way combine at the end.
//  - Math unchanged: 2 v_pk_fma_f32 + v_min3_f32 per pair per query,
//    |t|^2 poisoned 1e30 past Lp, s2 folded once, clamp+sqrt at store.
//    Lp==0 -> d2=1e10 sentinel (matches ref sqrt(BIG)); q>=Lq -> 0.
//  - Pre-committed read: <=75us confirms single-dispatch (next: MFMA-ize
//    the scan); >=80us -> revert to R14 structure, attack main internals.

#define CHP 512   // pairs per staged chunk = 1024 points (12 KB LDS)
#define NQ  8     // queries per thread
typedef float f2 __attribute__((ext_vector_type(2)));

__global__ __launch_bounds__(256) void chamfer_one(
    const float* __restrict__ src, const float* __restrict__ tgt,
    const int* __restrict__ slen, const int* __restrict__ tlen,
    float* __restrict__ out)
{
    __shared__ float4 sh_xy[CHP];        // {x0,x1,y0,y1} per point-pair
    __shared__ f2     sh_n[CHP];         // {|t0|^2,|t1|^2}, 1e30 past Lp
    __shared__ float  sh_best[16][129];  // 16 search-split partials; stride
                                         // 129 -> write 4-way, read 0-way bc

    const int g    = blockIdx.x;         // 1024 = 32 rows x 32 slices
    const int row  = g >> 5, slice = g & 31;
    const int dir  = row >> 4, b = row & 15;
    const int tid  = threadIdx.x;

    const int Lq = dir ? tlen[b] : slen[b];   // query-side valid length
    const int Lp = dir ? slen[b] : tlen[b];   // search-side valid length

    float* op = out + row * 4096 + slice * 128;

    if (slice * 128 >= Lq) {             // whole slice padded -> zeros, done
        if (tid < 128) op[tid] = 0.f;
        return;
    }

    const float* Qp = dir ? tgt : src;
    const float* P  = dir ? src : tgt;

    // Thread t: queries qg*8..qg*8+7 (contiguous, 32B = 4x float2 per
    // thread), search sixteenth sh16. 16 thread-slots cover each query.
    const int qg = tid & 15, sh16 = tid >> 4;

    float mx[NQ], my[NQ], s2q[NQ], best[NQ];
    #pragma unroll
    for (int k = 0; k < NQ; ++k) {
        const float2 qv = ((const float2*)Qp)[b * 4096 + slice * 128 + qg * 8 + k];
        mx[k] = -2.f * qv.x;
        my[k] = -2.f * qv.y;
        s2q[k] = fmaf(qv.x, qv.x, qv.y * qv.y);
        best[k] = 3.0e38f;
    }

    const int npair = (Lp + 1) >> 1;
    const float4* Pp = (const float4*)P + b * 2048;   // pair-packed {x0,y0,x1,y1}

    for (int c0 = 0; c0 < npair; c0 += CHP) {
        const int npc = min(CHP, npair - c0);         // block-uniform
        __syncthreads();                               // protect prev chunk
        #pragma unroll
        for (int i = 0; i < 2; ++i) {
            const int p = tid + i * 256;
            if (p < npc) {
                const float4 pp = Pp[c0 + p];
                const int i0 = (c0 + p) * 2;
                const float n0 = (i0 + 0 < Lp) ? fmaf(pp.x, pp.x, pp.y * pp.y) : 1e30f;
                const float n1 = (i0 + 1 < Lp) ? fmaf(pp.z, pp.z, pp.w * pp.w) : 1e30f;
                sh_xy[p] = make_float4(pp.x, pp.z, pp.y, pp.w);  // {x0,x1,y0,y1}
                sh_n[p]  = f2{n0, n1};
            }
        }
        __syncthreads();

        // This thread's 32-pair sixteenth of the chunk. Uniform-j within a
        // 16-lane group -> broadcast-friendly LDS reads; per pair:
        // 2 ds_reads amortized over NQ=8 x (2 pk_fma + min3) = 48cy VALU.
        const int j0 = sh16 * 32;
        const int j1 = min(j0 + 32, npc);
        #pragma unroll 4
        for (int j = j0; j < j1; ++j) {
            const float4 xy = sh_xy[j];
            const f2 np = sh_n[j];
            const f2 xp = f2{xy.x, xy.y};
            const f2 yp = f2{xy.z, xy.w};
            #pragma unroll
            for (int k = 0; k < NQ; ++k) {
                f2 v = xp * mx[k] + np;        // pk_fma: n - 2qx*tx
                v = yp * my[k] + v;            // pk_fma: n - 2q.t
                best[k] = fminf(best[k], fminf(v.x, v.y));  // v_min3_f32
            }
        }
    }

    // Fold s2 and combine the 16 search-split partials in LDS.
    #pragma unroll
    for (int k = 0; k < NQ; ++k)
        sh_best[sh16][qg * 8 + k] = best[k] + s2q[k];
    __syncthreads();

    if (tid < 128) {
        float m = sh_best[0][tid];
        #pragma unroll
        for (int w = 1; w < 16; ++w)
            m = fminf(m, sh_best[w][tid]);
        const float d2 = (Lp == 0) ? 1e10f : m;   // empty search set -> BIG
        const int q = slice * 128 + tid;
        op[tid] = (q < Lq) ? sqrtf(fmaxf(d2, 0.f)) : 0.f;
    }
}

extern "C" void kernel_launch(void* const* d_in, const int* in_sizes, int n_in,
                              void* d_out, int out_size, void* d_ws, size_t ws_size,
                              hipStream_t stream) {
    const float* src = (const float*)d_in[0];   // [16,4096,2] f32
    const float* tgt = (const float*)d_in[1];   // [16,4096,2] f32
    const int* slen  = (const int*)d_in[2];     // [16] i32
    const int* tlen  = (const int*)d_in[3];     // [16] i32
    (void)d_ws; (void)ws_size;                  // no workspace, no init pass

    chamfer_one<<<1024, 256, 0, stream>>>(src, tgt, slen, tlen, (float*)d_out);
}